// Round 3
// baseline (374.756 us; speedup 1.0000x reference)
//
#include <hip/hip_runtime.h>

typedef unsigned short ushort_t;
typedef __attribute__((ext_vector_type(8))) __bf16 bf16x8;
typedef __attribute__((ext_vector_type(4))) float f32x4;

#define MARGIN 1.5e-3f
#define FT 8    // fixup tokens per block
#define FTP 12  // padded row length for xsT (48B rows: 16B-aligned, vectorizable)

__device__ __forceinline__ float bf2f(ushort_t u){
  union { unsigned int i; float f; } v; v.i = ((unsigned int)u) << 16; return v.f;
}
__device__ __forceinline__ ushort_t f2bf(float f){
  union { float f; unsigned int i; } v; v.f = f;
  unsigned int x = v.i;
  return (ushort_t)((x + 0x7fffu + ((x >> 16) & 1u)) >> 16);
}

// ---------------------------------------------------------------------------
// prep: weights -> bf16 in FRAGMENT-PACKED layout
//   WP[e][n>>4][k>>3][n&15][k&7]  (n = output row, k = reduction)
// so one wave MFMA B-fragment = one coalesced 1KB global_load_dwordx4 from L2.
// Wr2 -> bf16 hi + bf16 residual (lo). fp32 transposes for the fixup kernel.
// ---------------------------------------------------------------------------
__global__ __launch_bounds__(256) void k_prep(const float* __restrict__ We,
    const float* __restrict__ Wr1, const float* __restrict__ Wr2,
    ushort_t* __restrict__ WebP, ushort_t* __restrict__ W1bP,
    ushort_t* __restrict__ W2h, ushort_t* __restrict__ W2l,
    float* __restrict__ Wr1T, float* __restrict__ Wr2T)
{
  int idx = blockIdx.x*256 + threadIdx.x;
  if (idx < 1048576){
    int n = (idx >> 8) & 255, k = idx & 255;
    int dst = (idx & ~65535) + ((n>>4)<<12) + ((k>>3)<<7) + ((n&15)<<3) + (k&7);
    WebP[dst] = f2bf(We[idx]);
  }
  if (idx < 65536){
    int n = idx >> 8, k = idx & 255;
    W1bP[((n>>4)<<12) + ((k>>3)<<7) + ((n&15)<<3) + (k&7)] = f2bf(Wr1[idx]);
    int kk = idx >> 8, o = idx & 255;          // coalesced write, strided read
    Wr1T[idx] = Wr1[o*256 + kk];
  }
  if (idx < 4096){
    float w = Wr2[idx];
    ushort_t wh = f2bf(w);
    W2h[idx] = wh;
    W2l[idx] = f2bf(w - bf2f(wh));   // residual, captures next ~8 bits
    int k = idx >> 4, e = idx & 15;
    Wr2T[idx] = Wr2[e*256 + k];
  }
}

// ---------------------------------------------------------------------------
// Fused GEMM1 + logits + top2 + softmax + near-tie flagging. 64 tokens/block.
// R8: x-tile staged ONCE (bf16, chunk-XOR-swizzled LDS); W1 B-fragments read
// directly from L2-resident packed W1bP. NO barriers inside the K-loop.
// ---------------------------------------------------------------------------
__global__ __launch_bounds__(256) void r1r2_fused(const float* __restrict__ x,
    const ushort_t* __restrict__ W1bP, const float* __restrict__ br1,
    const ushort_t* __restrict__ W2h, const ushort_t* __restrict__ W2l,
    const float* __restrict__ br2,
    int* __restrict__ pid, float2* __restrict__ pAB,
    int* __restrict__ fixCnt, int* __restrict__ fixTok)
{
  __shared__ __align__(16) char smem[38144];
  ushort_t* xt = (ushort_t*)smem;              // 64 rows x 512B, chunk-swizzled
  ushort_t* hB = (ushort_t*)smem;              // 64 x 264 (reuse after K-loop)
  float*    lg = (float*)(smem + 33792);       // 64 x 17
  const int tid = threadIdx.x;
  const int wave = tid>>6, lane = tid&63, q = lane>>4, col = lane&15;
  const int tok0 = blockIdx.x*64;

  // stage x-tile once: thread handles 8 chunks of 8 floats
  #pragma unroll
  for (int j=0;j<8;j++){
    int ci = j*256 + tid, row = ci>>5, c = ci&31;
    f32x4 v0 = *(const f32x4*)&x[(tok0+row)*256 + c*8];
    f32x4 v1 = *(const f32x4*)&x[(tok0+row)*256 + c*8 + 4];
    union { uint4 u; ushort_t s[8]; } pk;
    pk.s[0]=f2bf(v0[0]); pk.s[1]=f2bf(v0[1]); pk.s[2]=f2bf(v0[2]); pk.s[3]=f2bf(v0[3]);
    pk.s[4]=f2bf(v1[0]); pk.s[5]=f2bf(v1[1]); pk.s[6]=f2bf(v1[2]); pk.s[7]=f2bf(v1[3]);
    *(uint4*)&xt[row*256 + ((c ^ (row&7))<<3)] = pk.u;
  }
  __syncthreads();

  f32x4 acc[4][4];
  #pragma unroll
  for (int i=0;i<4;i++)
    #pragma unroll
    for (int j=0;j<4;j++) acc[i][j] = f32x4{0.f,0.f,0.f,0.f};

  // K-loop: no barriers; b frags straight from L2-resident packed weights
  const ushort_t* bp = W1bP + (wave*4)*4096 + q*128 + col*8;
  #pragma unroll
  for (int kc=0;kc<4;kc++){
    #pragma unroll
    for (int kk=0;kk<2;kk++){
      const int k8 = kc*8 + kk*4 + q;
      bf16x8 a[4];
      #pragma unroll
      for (int rf=0;rf<4;rf++)
        a[rf] = *(const bf16x8*)&xt[(rf*16+col)*256 + ((k8 ^ (col&7))<<3)];
      #pragma unroll
      for (int cf=0;cf<4;cf++){
        bf16x8 b = *(const bf16x8*)&bp[cf*4096 + (kc*8+kk*4)*128];
        #pragma unroll
        for (int rf=0;rf<4;rf++)
          acc[rf][cf] = __builtin_amdgcn_mfma_f32_16x16x32_bf16(a[rf], b, acc[rf][cf], 0,0,0);
      }
    }
  }
  __syncthreads();
  // h = leaky(acc + br1) -> bf16 into hB (overwrites xt; all reads done)
  {
    float br1v[4];
    #pragma unroll
    for (int cf=0;cf<4;cf++) br1v[cf] = br1[wave*64 + cf*16 + col];
    #pragma unroll
    for (int rf=0;rf<4;rf++)
      #pragma unroll
      for (int cf=0;cf<4;cf++){
        int o = wave*64 + cf*16 + col;
        #pragma unroll
        for (int r=0;r<4;r++){
          int row = rf*16 + q*4 + r;
          float p = acc[rf][cf][r] + br1v[cf];
          p = p > 0.f ? p : 0.01f*p;
          hB[row*264 + o] = f2bf(p);
        }
      }
  }
  __syncthreads();
  // logits[64x16] = h @ Wr2^T via MFMA; wave handles its 16-token m-tile
  {
    f32x4 acc2 = f32x4{0.f,0.f,0.f,0.f};
    #pragma unroll
    for (int c2=0;c2<8;c2++){
      bf16x8 a2 = *(const bf16x8*)&hB[(wave*16+col)*264 + c2*32 + q*8];
      bf16x8 bh = *(const bf16x8*)&W2h[col*256 + c2*32 + q*8];
      bf16x8 bl = *(const bf16x8*)&W2l[col*256 + c2*32 + q*8];
      acc2 = __builtin_amdgcn_mfma_f32_16x16x32_bf16(a2, bh, acc2, 0,0,0);
      acc2 = __builtin_amdgcn_mfma_f32_16x16x32_bf16(a2, bl, acc2, 0,0,0);
    }
    #pragma unroll
    for (int r=0;r<4;r++) lg[(wave*16 + q*4 + r)*17 + col] = acc2[r];
  }
  __syncthreads();
  if (tid < 64){
    const int tok = tok0 + tid;
    float v[16];
    #pragma unroll
    for (int e=0;e<16;e++) v[e] = lg[tid*17 + e] + br2[e];
    float best=-3.4e38f, sec=-3.4e38f, thr=-3.4e38f; int b1=0, b2=0;
    #pragma unroll
    for (int e=0;e<16;e++){
      float val = v[e];
      if (val > best){ thr=sec; sec=best; b2=b1; best=val; b1=e; }
      else if (val > sec){ thr=sec; sec=val; b2=e; }
      else if (val > thr){ thr=val; }
    }
    float ex = expf(sec - best);
    float s = 1.f + ex;
    float p1 = 1.f/s, p2 = ex/s;
    int eA = b1 < b2 ? b1 : b2;
    int eB = b1 < b2 ? b2 : b1;
    float pA = b1 < b2 ? p1 : p2;
    float pB = b1 < b2 ? p2 : p1;
    pid[tok] = eA*16 + eB;
    pAB[tok] = make_float2(pA, pB);
    if (sec - thr < MARGIN){
      int slot = atomicAdd(fixCnt, 1);
      fixTok[slot] = tok;
    }
  }
}

// ---------------------------------------------------------------------------
// fp64 exact router recompute for near-tie tokens (coalesced transposed
// weights; xsT broadcast reads).
// ---------------------------------------------------------------------------
__global__ __launch_bounds__(256) void k_fixup(const float* __restrict__ x,
    const float* __restrict__ Wr1T, const float* __restrict__ br1,
    const float* __restrict__ Wr2T, const float* __restrict__ br2,
    const int* __restrict__ fixCnt, const int* __restrict__ fixTok,
    int* __restrict__ pid, float2* __restrict__ pAB)
{
  __shared__ __align__(16) float xsT[256][FTP];  // 12 KB, rows 48B (16B-aligned)
  __shared__ double hs[FT*256];                  // 16 KB
  __shared__ double lgs[FT][16];
  const int tid = threadIdx.x;
  const int n = *fixCnt;
  for (int base = blockIdx.x*FT; base < n; base += gridDim.x*FT){
    const int nt = min(FT, n - base);
    __syncthreads();
    // stage x for up to FT tokens, transposed: xsT[c][t]
    for (int i = tid; i < nt*256; i += 256){
      int t = i >> 8, c = i & 255;               // coalesced read per token row
      xsT[c][t] = x[fixTok[base + t]*256 + c];
    }
    __syncthreads();
    // layer 1: thread o computes h[t][o] for all FT tokens.
    {
      const int o = tid;
      double acc[FT];
      #pragma unroll
      for (int t=0;t<FT;t++) acc[t] = 0.0;
      #pragma unroll 4
      for (int k=0;k<256;k++){
        double w = (double)Wr1T[k*256 + o];
        #pragma unroll
        for (int t=0;t<FT;t++)
          acc[t] += (double)xsT[k][t] * w;
      }
      double b = (double)br1[o];
      #pragma unroll
      for (int t=0;t<FT;t++){
        double v = acc[t] + b;
        hs[t*256 + o] = v > 0.0 ? v : 0.01*v;
      }
    }
    __syncthreads();
    // layer 2: 128 threads, (t,e) = (tid>>4, tid&15); Wr2T[k*16+e] coalesced
    if (tid < FT*16){
      const int t = tid >> 4, e = tid & 15;
      double a0=0, a1=0;
      #pragma unroll 4
      for (int k=0;k<256;k+=2){
        a0 += hs[t*256 + k]     * (double)Wr2T[k*16 + e];
        a1 += hs[t*256 + k + 1] * (double)Wr2T[(k+1)*16 + e];
      }
      lgs[t][e] = (a0 + a1) + (double)br2[e];
    }
    __syncthreads();
    if (tid < nt){
      const int tok = fixTok[base + tid];
      double best=-1e300, sec=-1e300; int b1=0, b2=0;
      #pragma unroll
      for (int e=0;e<16;e++){
        double val = lgs[tid][e];
        if (val > best){ sec=best; b2=b1; best=val; b1=e; }
        else if (val > sec){ sec=val; b2=e; }
      }
      double ex = exp(sec - best);
      double s = 1.0 + ex;
      double p1 = 1.0/s, p2 = ex/s;
      int eA = b1 < b2 ? b1 : b2;
      int eB = b1 < b2 ? b2 : b1;
      float pA = (float)(b1 < b2 ? p1 : p2);
      float pB = (float)(b1 < b2 ? p2 : p1);
      pid[tok] = eA*16 + eB;
      pAB[tok] = make_float2(pA, pB);
    }
  }
}

__global__ __launch_bounds__(256) void k_hist(const int* __restrict__ pid, int* __restrict__ cnt)
{
  __shared__ int hc[256];
  const int tid = threadIdx.x;
  hc[tid] = 0; __syncthreads();
  atomicAdd(&hc[pid[blockIdx.x*256 + tid]], 1);
  __syncthreads();
  if (hc[tid]) atomicAdd(&cnt[tid], hc[tid]);
}

__global__ __launch_bounds__(256) void k_scan(int* __restrict__ cnt, int* __restrict__ cur,
    int* __restrict__ off, int* __restrict__ tileOff)
{
  __shared__ int sc[256];
  const int tid = threadIdx.x;
  int c = cnt[tid];
  sc[tid] = c; __syncthreads();
  for (int s=1;s<256;s<<=1){ int v = (tid>=s)? sc[tid-s]:0; __syncthreads(); sc[tid]+=v; __syncthreads(); }
  int inc = sc[tid];
  off[tid] = inc - c;
  cur[tid] = inc - c;
  if (tid==255) off[256] = inc;
  int tc = (c+63)>>6;
  __syncthreads();
  sc[tid] = tc; __syncthreads();
  for (int s=1;s<256;s<<=1){ int v = (tid>=s)? sc[tid-s]:0; __syncthreads(); sc[tid]+=v; __syncthreads(); }
  tileOff[tid] = sc[tid] - tc;
  if (tid==255) tileOff[256] = sc[tid];
}

__global__ __launch_bounds__(256) void k_scatter(const int* __restrict__ pid,
    int* __restrict__ cur, int* __restrict__ sortedTok)
{
  int b = blockIdx.x*256 + threadIdx.x;
  int p = pid[b];
  int slot = atomicAdd(&cur[p], 1);
  sortedTok[slot] = b;
}

// ---------------------------------------------------------------------------
// Expert pair GEMM — R8 rewrite:
//  * x-tile staged ONCE to swizzled LDS (bf16); both experts in one K-sweep.
//  * B fragments read directly from L2-resident packed WebP (coalesced 1KB
//    per wave-instr) — no B LDS, NO barriers in the K-loop.
//  * probs in epilogue, biases folded into acc init.
//  * __launch_bounds__(256,3): cap VGPR at 170 -> 3 waves/SIMD (R7 lesson:
//    172 VGPR tips to 2 waves/SIMD and occupancy collapses).
// ---------------------------------------------------------------------------
__global__ __launch_bounds__(256,3) void k_expert(const float* __restrict__ x,
    const ushort_t* __restrict__ WebP, const float* __restrict__ be,
    const int* __restrict__ off, const int* __restrict__ tileOff,
    const int* __restrict__ sortedTok, const float2* __restrict__ pAB,
    float* __restrict__ out)
{
  const int totTiles = tileOff[256];
  const int bid = blockIdx.x;
  if (bid >= totTiles) return;
  __shared__ __align__(16) char smem[33792];
  ushort_t* xt = (ushort_t*)smem;          // 64 rows x 512B, chunk-swizzled
  __shared__ int toks[64];
  __shared__ float pAs[64], pBs[64];
  __shared__ int sh_p;
  const int tid = threadIdx.x;
  if (tid == 0){
    int lo=0, hi=255;
    while (lo < hi){ int mid=(lo+hi+1)>>1; if (tileOff[mid] <= bid) lo=mid; else hi=mid-1; }
    sh_p = lo;
  }
  __syncthreads();
  const int p = sh_p;
  const int tstart = off[p] + (bid - tileOff[p])*64;
  const int nt = min(64, off[p+1] - tstart);
  if (tid < 64){
    if (tid < nt){
      int t = sortedTok[tstart + tid];
      toks[tid] = t;
      float2 ab = pAB[t];
      pAs[tid] = ab.x; pBs[tid] = ab.y;
    } else { toks[tid] = -1; pAs[tid]=0.f; pBs[tid]=0.f; }
  }
  __syncthreads();

  // stage x-tile once (gathered rows; pad rows read token 0, never stored)
  #pragma unroll
  for (int j=0;j<8;j++){
    int ci = j*256 + tid, row = ci>>5, c = ci&31;
    int t = toks[row]; t = t < 0 ? 0 : t;
    f32x4 v0 = *(const f32x4*)&x[t*256 + c*8];
    f32x4 v1 = *(const f32x4*)&x[t*256 + c*8 + 4];
    union { uint4 u; ushort_t s[8]; } pk;
    pk.s[0]=f2bf(v0[0]); pk.s[1]=f2bf(v0[1]); pk.s[2]=f2bf(v0[2]); pk.s[3]=f2bf(v0[3]);
    pk.s[4]=f2bf(v1[0]); pk.s[5]=f2bf(v1[1]); pk.s[6]=f2bf(v1[2]); pk.s[7]=f2bf(v1[3]);
    *(uint4*)&xt[row*256 + ((c ^ (row&7))<<3)] = pk.u;
  }
  __syncthreads();

  const int wave = tid>>6, lane = tid&63, q = lane>>4, col = lane&15;
  const int eA = p >> 4, eB = p & 15;

  // acc init = expert bias broadcast (out = pA*(x.WA + bA) + pB*(x.WB + bB))
  f32x4 accA[4][4], accB[4][4];
  #pragma unroll
  for (int cf=0;cf<4;cf++){
    int o = wave*64 + cf*16 + col;
    float vA = be[eA*256 + o], vB = be[eB*256 + o];
    #pragma unroll
    for (int rf=0;rf<4;rf++){
      accA[rf][cf] = f32x4{vA,vA,vA,vA};
      accB[rf][cf] = f32x4{vB,vB,vB,vB};
    }
  }

  // K-loop: no barriers; b frags straight from L2-resident packed weights
  const ushort_t* bAp = WebP + eA*65536 + (wave*4)*4096 + q*128 + col*8;
  const ushort_t* bBp = WebP + eB*65536 + (wave*4)*4096 + q*128 + col*8;
  for (int kc=0;kc<4;kc++){
    #pragma unroll
    for (int kk=0;kk<2;kk++){
      const int k8 = kc*8 + kk*4 + q;
      bf16x8 a[4];
      #pragma unroll
      for (int rf=0;rf<4;rf++)
        a[rf] = *(const bf16x8*)&xt[(rf*16+col)*256 + ((k8 ^ (col&7))<<3)];
      #pragma unroll
      for (int cf=0;cf<4;cf++){
        bf16x8 vA = *(const bf16x8*)&bAp[cf*4096 + (kc*8+kk*4)*128];
        bf16x8 vB = *(const bf16x8*)&bBp[cf*4096 + (kc*8+kk*4)*128];
        #pragma unroll
        for (int rf=0;rf<4;rf++)
          accA[rf][cf] = __builtin_amdgcn_mfma_f32_16x16x32_bf16(a[rf], vA, accA[rf][cf], 0,0,0);
        #pragma unroll
        for (int rf=0;rf<4;rf++)
          accB[rf][cf] = __builtin_amdgcn_mfma_f32_16x16x32_bf16(a[rf], vB, accB[rf][cf], 0,0,0);
      }
    }
  }

  // epilogue: out = leaky(pA*accA + pB*accB); 2-phase fp32 LDS transpose
  float* obuf = (float*)smem;   // 32 x 264 fp32 = 33792 B (xt dead)
  #pragma unroll
  for (int ph=0; ph<2; ++ph){
    __syncthreads();
    #pragma unroll
    for (int cf=0;cf<4;cf++){
      int o = wave*64 + cf*16 + col;
      #pragma unroll
      for (int rr=0;rr<2;rr++){
        int rf = ph*2 + rr;
        #pragma unroll
        for (int r=0;r<4;r++){
          int row = rf*16 + q*4 + r;
          float v = pAs[row]*accA[rf][cf][r] + pBs[row]*accB[rf][cf][r];
          v = v > 0.f ? v : 0.01f*v;
          obuf[(row - ph*32)*264 + o] = v;
        }
      }
    }
    __syncthreads();
    #pragma unroll
    for (int j=0;j<8;j++){
      int idx = j*256 + tid;
      int lrow = idx>>6, c4 = idx&63;
      int row = ph*32 + lrow;
      int t = toks[row];
      if (t >= 0)
        *(f32x4*)&out[t*256 + c4*4] = *(const f32x4*)&obuf[lrow*264 + c4*4];
    }
  }
}

// ---------------------------------------------------------------------------
extern "C" void kernel_launch(void* const* d_in, const int* in_sizes, int n_in,
                              void* d_out, int out_size, void* d_ws, size_t ws_size,
                              hipStream_t stream)
{
  const float* x   = (const float*)d_in[0];
  const float* Wr1 = (const float*)d_in[1];
  const float* br1 = (const float*)d_in[2];
  const float* Wr2 = (const float*)d_in[3];
  const float* br2 = (const float*)d_in[4];
  const float* We  = (const float*)d_in[5];
  const float* be  = (const float*)d_in[6];
  float* out = (float*)d_out;

  // Workspace layout (non-overlapping, 16B-aligned)
  char* ws = (char*)d_ws;
  ushort_t* WebP     = (ushort_t*)ws;                 // [0,        2097152)
  ushort_t* W1bP     = (ushort_t*)(ws + 2097152);     // [2097152,  2228224)
  ushort_t* W2h      = (ushort_t*)(ws + 2228224);     // [2228224,  2236416)
  ushort_t* W2l      = (ushort_t*)(ws + 2236416);     // [2236416,  2244608)
  int*      pid      = (int*)(ws + 2244608);          // [2244608,  2506752)
  float2*   pAB      = (float2*)(ws + 2506752);       // [2506752,  3031040)
  int*      sortedTok= (int*)(ws + 3031040);          // [3031040,  3293184)
  int*      fixTok   = (int*)(ws + 3293184);          // [3293184,  3555328)
  int*      cnt      = (int*)(ws + 3555328);          // 256 ints
  int*      fixCnt   = cnt + 256;                     // 1 int
  int*      cur      = cnt + 272;                     // 256 ints
  int*      off      = cnt + 528;                     // 257 ints
  int*      tileOff  = cnt + 785;                     // 257 ints
  float*    Wr1T     = (float*)(ws + 3559504);        // 256KB fp32 transpose
  float*    Wr2T     = (float*)(ws + 3821648);        // 16KB fp32 transpose

  hipMemsetAsync(cnt, 0, 257*sizeof(int), stream);
  k_prep    <<<4096, 256, 0, stream>>>(We, Wr1, Wr2, WebP, W1bP, W2h, W2l, Wr1T, Wr2T);
  r1r2_fused<<<1024, 256, 0, stream>>>(x, W1bP, br1, W2h, W2l, br2, pid, pAB, fixCnt, fixTok);
  k_fixup   <<<512,  256, 0, stream>>>(x, Wr1T, br1, Wr2T, br2, fixCnt, fixTok, pid, pAB);
  k_hist    <<<256,  256, 0, stream>>>(pid, cnt);
  k_scan    <<<1,    256, 0, stream>>>(cnt, cur, off, tileOff);
  k_scatter <<<256,  256, 0, stream>>>(pid, cur, sortedTok);
  k_expert  <<<1160, 256, 0, stream>>>(x, WebP, be, off, tileOff, sortedTok, pAB, out);
}

// Round 4
// 313.022 us; speedup vs baseline: 1.1972x; 1.1972x over previous
//
#include <hip/hip_runtime.h>

typedef unsigned short ushort_t;
typedef __attribute__((ext_vector_type(8))) __bf16 bf16x8;
typedef __attribute__((ext_vector_type(4))) float f32x4;

#define MARGIN 1.5e-3f
#define FT 8    // fixup tokens per block
#define FTP 12  // padded row length for xsT (48B rows: 16B-aligned, vectorizable)

__device__ __forceinline__ float bf2f(ushort_t u){
  union { unsigned int i; float f; } v; v.i = ((unsigned int)u) << 16; return v.f;
}
__device__ __forceinline__ ushort_t f2bf(float f){
  union { float f; unsigned int i; } v; v.f = f;
  unsigned int x = v.i;
  return (ushort_t)((x + 0x7fffu + ((x >> 16) & 1u)) >> 16);
}
// async global->LDS, 16B per lane; LDS dest is wave-uniform base + lane*16
__device__ __forceinline__ void async_load16(const void* g, void* l){
  __builtin_amdgcn_global_load_lds((const __attribute__((address_space(1))) void*)g,
                                   (__attribute__((address_space(3))) void*)l, 16, 0, 0);
}

// ---------------------------------------------------------------------------
// prep: We -> bf16 FRAGMENT-PACKED  WP[e][n>>4][k>>3][n&15][k&7]  (k_expert
// reads B-fragments as one coalesced 1KB wave-load from L2). Wr1 -> bf16
// row-major (r1r2 stages it via global_load_lds). Wr2 -> bf16 hi+lo split.
// fp32 transposes Wr1T/Wr2T for the fp64 fixup kernel.
// ---------------------------------------------------------------------------
__global__ __launch_bounds__(256) void k_prep(const float* __restrict__ We,
    const float* __restrict__ Wr1, const float* __restrict__ Wr2,
    ushort_t* __restrict__ WebP, ushort_t* __restrict__ W1b,
    ushort_t* __restrict__ W2h, ushort_t* __restrict__ W2l,
    float* __restrict__ Wr1T, float* __restrict__ Wr2T)
{
  int idx = blockIdx.x*256 + threadIdx.x;
  if (idx < 1048576){
    int n = (idx >> 8) & 255, k = idx & 255;
    int dst = (idx & ~65535) + ((n>>4)<<12) + ((k>>3)<<7) + ((n&15)<<3) + (k&7);
    WebP[dst] = f2bf(We[idx]);
  }
  if (idx < 65536){
    W1b[idx] = f2bf(Wr1[idx]);
    int k = idx >> 8, o = idx & 255;          // coalesced write, strided read
    Wr1T[idx] = Wr1[o*256 + k];
  }
  if (idx < 4096){
    float w = Wr2[idx];
    ushort_t wh = f2bf(w);
    W2h[idx] = wh;
    W2l[idx] = f2bf(w - bf2f(wh));   // residual, captures next ~8 bits
    int k = idx >> 4, e = idx & 15;
    Wr2T[idx] = Wr2[e*256 + k];
  }
}

// ---------------------------------------------------------------------------
// Fused GEMM1 (bf16 MFMA) + logits MFMA + top2 + softmax + near-tie flagging.
// 64 tokens/block. Proven R7 version: x loads issued BEFORE the async B loads
// so the f2bf conversion's register wait doesn't drain the whole B stream.
// ---------------------------------------------------------------------------
__global__ __launch_bounds__(256) void r1r2_fused(const float* __restrict__ x,
    const ushort_t* __restrict__ W1b, const float* __restrict__ br1,
    const ushort_t* __restrict__ W2h, const ushort_t* __restrict__ W2l,
    const float* __restrict__ br2,
    int* __restrict__ pid, float2* __restrict__ pAB,
    int* __restrict__ fixCnt, int* __restrict__ fixTok)
{
  __shared__ __align__(16) char smem[46336];
  ushort_t* As = (ushort_t*)smem;              // 64 x 72
  char*     Bs = smem + 9216;                  // 256 rows x 128B, XOR-swizzled
  ushort_t* hB = (ushort_t*)smem;              // 64 x 264 (reuse after K-loop)
  float*    lg = (float*)(smem + 41984);       // 64 x 17
  const int tid = threadIdx.x;
  const int wave = tid>>6, lane = tid&63, q = lane>>4, col = lane&15;
  const int tok0 = blockIdx.x*64;

  f32x4 acc[4][4];
  #pragma unroll
  for (int i=0;i<4;i++)
    #pragma unroll
    for (int j=0;j<4;j++) acc[i][j] = f32x4{0.f,0.f,0.f,0.f};

  for (int kc = 0; kc < 4; ++kc){
    const int kb = kc*64;
    __syncthreads();
    // x loads FIRST (their latency overlaps the B async issue + latency)
    f32x4 xv[2][2];
    #pragma unroll
    for (int j=0;j<2;j++){
      int idx = j*256 + tid, row = idx>>3, c8 = idx&7;
      xv[j][0] = *(const f32x4*)&x[(tok0+row)*256 + kb + c8*8];
      xv[j][1] = *(const f32x4*)&x[(tok0+row)*256 + kb + c8*8 + 4];
    }
    // B: 32KB via global_load_lds; wave stages rows [wave*64, wave*64+64)
    #pragma unroll
    for (int i=0;i<8;i++){
      int r0 = wave*64 + i*8;
      int grow = r0 + (lane>>3);
      int kc8 = (lane&7) ^ (grow&7);
      async_load16(W1b + grow*256 + kb + kc8*8, Bs + r0*128);
    }
    // A: convert + write (waits only on x regs; B stream still in flight)
    #pragma unroll
    for (int j=0;j<2;j++){
      int idx = j*256 + tid, row = idx>>3, c8 = idx&7;
      union { uint4 u; ushort_t s[8]; } pk;
      pk.s[0]=f2bf(xv[j][0][0]); pk.s[1]=f2bf(xv[j][0][1]); pk.s[2]=f2bf(xv[j][0][2]); pk.s[3]=f2bf(xv[j][0][3]);
      pk.s[4]=f2bf(xv[j][1][0]); pk.s[5]=f2bf(xv[j][1][1]); pk.s[6]=f2bf(xv[j][1][2]); pk.s[7]=f2bf(xv[j][1][3]);
      *(uint4*)&As[row*72 + c8*8] = pk.u;
    }
    __syncthreads();
    #pragma unroll
    for (int kk=0;kk<2;kk++){
      bf16x8 a[4], b[4];
      #pragma unroll
      for (int rf=0;rf<4;rf++) a[rf] = *(const bf16x8*)&As[(rf*16+col)*72 + kk*32 + q*8];
      #pragma unroll
      for (int cf=0;cf<4;cf++){
        int n = wave*64 + cf*16 + col;
        b[cf] = *(const bf16x8*)(Bs + n*128 + (((kk*4+q) ^ (n&7))*16));
      }
      #pragma unroll
      for (int rf=0;rf<4;rf++)
        #pragma unroll
        for (int cf=0;cf<4;cf++)
          acc[rf][cf] = __builtin_amdgcn_mfma_f32_16x16x32_bf16(a[rf], b[cf], acc[rf][cf], 0,0,0);
    }
  }
  __syncthreads();
  // h = leaky(acc + br1) -> bf16 into hB
  {
    float br1v[4];
    #pragma unroll
    for (int cf=0;cf<4;cf++) br1v[cf] = br1[wave*64 + cf*16 + col];
    #pragma unroll
    for (int rf=0;rf<4;rf++)
      #pragma unroll
      for (int cf=0;cf<4;cf++){
        int o = wave*64 + cf*16 + col;
        #pragma unroll
        for (int r=0;r<4;r++){
          int row = rf*16 + q*4 + r;
          float p = acc[rf][cf][r] + br1v[cf];
          p = p > 0.f ? p : 0.01f*p;
          hB[row*264 + o] = f2bf(p);
        }
      }
  }
  __syncthreads();
  // logits[64x16] = h @ Wr2^T via MFMA; wave handles its 16-token m-tile
  {
    f32x4 acc2 = f32x4{0.f,0.f,0.f,0.f};
    #pragma unroll
    for (int c2=0;c2<8;c2++){
      bf16x8 a2 = *(const bf16x8*)&hB[(wave*16+col)*264 + c2*32 + q*8];
      bf16x8 bh = *(const bf16x8*)&W2h[col*256 + c2*32 + q*8];
      bf16x8 bl = *(const bf16x8*)&W2l[col*256 + c2*32 + q*8];
      acc2 = __builtin_amdgcn_mfma_f32_16x16x32_bf16(a2, bh, acc2, 0,0,0);
      acc2 = __builtin_amdgcn_mfma_f32_16x16x32_bf16(a2, bl, acc2, 0,0,0);
    }
    #pragma unroll
    for (int r=0;r<4;r++) lg[(wave*16 + q*4 + r)*17 + col] = acc2[r];
  }
  __syncthreads();
  if (tid < 64){
    const int tok = tok0 + tid;
    float v[16];
    #pragma unroll
    for (int e=0;e<16;e++) v[e] = lg[tid*17 + e] + br2[e];
    float best=-3.4e38f, sec=-3.4e38f, thr=-3.4e38f; int b1=0, b2=0;
    #pragma unroll
    for (int e=0;e<16;e++){
      float val = v[e];
      if (val > best){ thr=sec; sec=best; b2=b1; best=val; b1=e; }
      else if (val > sec){ thr=sec; sec=val; b2=e; }
      else if (val > thr){ thr=val; }
    }
    float ex = expf(sec - best);
    float s = 1.f + ex;
    float p1 = 1.f/s, p2 = ex/s;
    int eA = b1 < b2 ? b1 : b2;
    int eB = b1 < b2 ? b2 : b1;
    float pA = b1 < b2 ? p1 : p2;
    float pB = b1 < b2 ? p2 : p1;
    pid[tok] = eA*16 + eB;
    pAB[tok] = make_float2(pA, pB);
    if (sec - thr < MARGIN){
      int slot = atomicAdd(fixCnt, 1);
      fixTok[slot] = tok;
    }
  }
}

// ---------------------------------------------------------------------------
// fp64 exact router recompute for near-tie tokens (coalesced transposed
// weights; xsT broadcast reads).
// ---------------------------------------------------------------------------
__global__ __launch_bounds__(256) void k_fixup(const float* __restrict__ x,
    const float* __restrict__ Wr1T, const float* __restrict__ br1,
    const float* __restrict__ Wr2T, const float* __restrict__ br2,
    const int* __restrict__ fixCnt, const int* __restrict__ fixTok,
    int* __restrict__ pid, float2* __restrict__ pAB)
{
  __shared__ __align__(16) float xsT[256][FTP];  // 12 KB, rows 48B (16B-aligned)
  __shared__ double hs[FT*256];                  // 16 KB
  __shared__ double lgs[FT][16];
  const int tid = threadIdx.x;
  const int n = *fixCnt;
  for (int base = blockIdx.x*FT; base < n; base += gridDim.x*FT){
    const int nt = min(FT, n - base);
    __syncthreads();
    // stage x for up to FT tokens, transposed: xsT[c][t]
    for (int i = tid; i < nt*256; i += 256){
      int t = i >> 8, c = i & 255;               // coalesced read per token row
      xsT[c][t] = x[fixTok[base + t]*256 + c];
    }
    __syncthreads();
    // layer 1: thread o computes h[t][o] for all FT tokens.
    {
      const int o = tid;
      double acc[FT];
      #pragma unroll
      for (int t=0;t<FT;t++) acc[t] = 0.0;
      #pragma unroll 4
      for (int k=0;k<256;k++){
        double w = (double)Wr1T[k*256 + o];
        #pragma unroll
        for (int t=0;t<FT;t++)
          acc[t] += (double)xsT[k][t] * w;
      }
      double b = (double)br1[o];
      #pragma unroll
      for (int t=0;t<FT;t++){
        double v = acc[t] + b;
        hs[t*256 + o] = v > 0.0 ? v : 0.01*v;
      }
    }
    __syncthreads();
    // layer 2: 128 threads, (t,e) = (tid>>4, tid&15); Wr2T[k*16+e] coalesced
    if (tid < FT*16){
      const int t = tid >> 4, e = tid & 15;
      double a0=0, a1=0;
      #pragma unroll 4
      for (int k=0;k<256;k+=2){
        a0 += hs[t*256 + k]     * (double)Wr2T[k*16 + e];
        a1 += hs[t*256 + k + 1] * (double)Wr2T[(k+1)*16 + e];
      }
      lgs[t][e] = (a0 + a1) + (double)br2[e];
    }
    __syncthreads();
    if (tid < nt){
      const int tok = fixTok[base + tid];
      double best=-1e300, sec=-1e300; int b1=0, b2=0;
      #pragma unroll
      for (int e=0;e<16;e++){
        double val = lgs[tid][e];
        if (val > best){ sec=best; b2=b1; best=val; b1=e; }
        else if (val > sec){ sec=val; b2=e; }
      }
      double ex = exp(sec - best);
      double s = 1.0 + ex;
      double p1 = 1.0/s, p2 = ex/s;
      int eA = b1 < b2 ? b1 : b2;
      int eB = b1 < b2 ? b2 : b1;
      float pA = (float)(b1 < b2 ? p1 : p2);
      float pB = (float)(b1 < b2 ? p2 : p1);
      pid[tok] = eA*16 + eB;
      pAB[tok] = make_float2(pA, pB);
    }
  }
}

__global__ __launch_bounds__(256) void k_hist(const int* __restrict__ pid, int* __restrict__ cnt)
{
  __shared__ int hc[256];
  const int tid = threadIdx.x;
  hc[tid] = 0; __syncthreads();
  atomicAdd(&hc[pid[blockIdx.x*256 + tid]], 1);
  __syncthreads();
  if (hc[tid]) atomicAdd(&cnt[tid], hc[tid]);
}

// tiles are 32 tokens now: tc = ceil(c/32)
__global__ __launch_bounds__(256) void k_scan(int* __restrict__ cnt, int* __restrict__ cur,
    int* __restrict__ off, int* __restrict__ tileOff)
{
  __shared__ int sc[256];
  const int tid = threadIdx.x;
  int c = cnt[tid];
  sc[tid] = c; __syncthreads();
  for (int s=1;s<256;s<<=1){ int v = (tid>=s)? sc[tid-s]:0; __syncthreads(); sc[tid]+=v; __syncthreads(); }
  int inc = sc[tid];
  off[tid] = inc - c;
  cur[tid] = inc - c;
  if (tid==255) off[256] = inc;
  int tc = (c+31)>>5;
  __syncthreads();
  sc[tid] = tc; __syncthreads();
  for (int s=1;s<256;s<<=1){ int v = (tid>=s)? sc[tid-s]:0; __syncthreads(); sc[tid]+=v; __syncthreads(); }
  tileOff[tid] = sc[tid] - tc;
  if (tid==255) tileOff[256] = sc[tid];
}

__global__ __launch_bounds__(256) void k_scatter(const int* __restrict__ pid,
    int* __restrict__ cur, int* __restrict__ sortedTok)
{
  int b = blockIdx.x*256 + threadIdx.x;
  int p = pid[b];
  int slot = atomicAdd(&cur[p], 1);
  sortedTok[slot] = b;
}

// ---------------------------------------------------------------------------
// Expert pair GEMM — R9:
//  * 32-token tiles; DUAL prob-scaled A tiles (xtA=pA*x, xtB=pB*x, bf16,
//    chunk-XOR-swizzled) -> SINGLE accumulator set (32 VGPR, no spill risk).
//  * biases folded into acc init: acc0 = pA*bA + pB*bB per element.
//  * B fragments straight from L2-resident packed WebP (coalesced 1KB/wave),
//    NO barriers in the K-loop.
//  * ~35 KB LDS -> 4 blocks/CU; NO forced launch bound (R8 lesson: forcing
//    VGPR below live state spills accumulators to scratch = 163MB HBM writes).
// ---------------------------------------------------------------------------
__global__ __launch_bounds__(256) void k_expert(const float* __restrict__ x,
    const ushort_t* __restrict__ WebP, const float* __restrict__ be,
    const int* __restrict__ off, const int* __restrict__ tileOff,
    const int* __restrict__ sortedTok, const float2* __restrict__ pAB,
    float* __restrict__ out)
{
  const int totTiles = tileOff[256];
  const int bid = blockIdx.x;
  if (bid >= totTiles) return;
  __shared__ __align__(16) char smem[34048];
  ushort_t* xtA = (ushort_t*)smem;            // 32 rows x 512B  [0, 16384)
  ushort_t* xtB = (ushort_t*)(smem + 16384);  // 32 rows x 512B  [16384, 32768)
  __shared__ int toks[32];
  __shared__ float pAs[32], pBs[32];
  __shared__ int sh_p;
  const int tid = threadIdx.x;
  if (tid == 0){
    int lo=0, hi=255;
    while (lo < hi){ int mid=(lo+hi+1)>>1; if (tileOff[mid] <= bid) lo=mid; else hi=mid-1; }
    sh_p = lo;
  }
  __syncthreads();
  const int p = sh_p;
  const int tstart = off[p] + (bid - tileOff[p])*32;
  const int nt = min(32, off[p+1] - tstart);
  if (tid < 32){
    if (tid < nt){
      int t = sortedTok[tstart + tid];
      toks[tid] = t;
      float2 ab = pAB[t];
      pAs[tid] = ab.x; pBs[tid] = ab.y;
    } else { toks[tid] = -1; pAs[tid]=0.f; pBs[tid]=0.f; }
  }
  __syncthreads();

  // stage dual prob-scaled x-tiles (pad rows: probs=0 -> zeros, never stored)
  #pragma unroll
  for (int j=0;j<4;j++){
    int ci = j*256 + tid, row = ci>>5, c = ci&31;
    int t = toks[row]; t = t < 0 ? 0 : t;
    float pA = pAs[row], pB = pBs[row];
    f32x4 v0 = *(const f32x4*)&x[t*256 + c*8];
    f32x4 v1 = *(const f32x4*)&x[t*256 + c*8 + 4];
    union { uint4 u; ushort_t s[8]; } pk;
    pk.s[0]=f2bf(v0[0]*pA); pk.s[1]=f2bf(v0[1]*pA); pk.s[2]=f2bf(v0[2]*pA); pk.s[3]=f2bf(v0[3]*pA);
    pk.s[4]=f2bf(v1[0]*pA); pk.s[5]=f2bf(v1[1]*pA); pk.s[6]=f2bf(v1[2]*pA); pk.s[7]=f2bf(v1[3]*pA);
    *(uint4*)&xtA[row*256 + ((c ^ (row&7))<<3)] = pk.u;
    pk.s[0]=f2bf(v0[0]*pB); pk.s[1]=f2bf(v0[1]*pB); pk.s[2]=f2bf(v0[2]*pB); pk.s[3]=f2bf(v0[3]*pB);
    pk.s[4]=f2bf(v1[0]*pB); pk.s[5]=f2bf(v1[1]*pB); pk.s[6]=f2bf(v1[2]*pB); pk.s[7]=f2bf(v1[3]*pB);
    *(uint4*)&xtB[row*256 + ((c ^ (row&7))<<3)] = pk.u;
  }
  __syncthreads();

  const int wave = tid>>6, lane = tid&63, q = lane>>4, col = lane&15;
  const int eA = p >> 4, eB = p & 15;

  // acc init = pA*bA + pB*bB per element (row-dependent probs, col-dep bias)
  float pa_r[8], pb_r[8];
  #pragma unroll
  for (int rf=0;rf<2;rf++)
    #pragma unroll
    for (int r=0;r<4;r++){
      int row = rf*16 + q*4 + r;
      pa_r[rf*4+r] = pAs[row]; pb_r[rf*4+r] = pBs[row];
    }
  f32x4 acc[2][4];
  #pragma unroll
  for (int cf=0;cf<4;cf++){
    int o = wave*64 + cf*16 + col;
    float bA_ = be[eA*256 + o], bB_ = be[eB*256 + o];
    #pragma unroll
    for (int rf=0;rf<2;rf++)
      #pragma unroll
      for (int r=0;r<4;r++)
        acc[rf][cf][r] = pa_r[rf*4+r]*bA_ + pb_r[rf*4+r]*bB_;
  }

  // K-loop: no barriers; B fragments straight from L2-resident packed weights
  const ushort_t* bAp = WebP + eA*65536 + (wave*4)*4096 + q*128 + col*8;
  const ushort_t* bBp = WebP + eB*65536 + (wave*4)*4096 + q*128 + col*8;
  #pragma unroll
  for (int kc=0;kc<4;kc++){
    #pragma unroll
    for (int kk=0;kk<2;kk++){
      const int k8 = kc*8 + kk*4 + q;
      bf16x8 aA[2], aB[2];
      #pragma unroll
      for (int rf=0;rf<2;rf++){
        aA[rf] = *(const bf16x8*)&xtA[(rf*16+col)*256 + ((k8 ^ (col&7))<<3)];
        aB[rf] = *(const bf16x8*)&xtB[(rf*16+col)*256 + ((k8 ^ (col&7))<<3)];
      }
      #pragma unroll
      for (int cf=0;cf<4;cf++){
        bf16x8 vA = *(const bf16x8*)&bAp[cf*4096 + (kc*8+kk*4)*128];
        bf16x8 vB = *(const bf16x8*)&bBp[cf*4096 + (kc*8+kk*4)*128];
        #pragma unroll
        for (int rf=0;rf<2;rf++)
          acc[rf][cf] = __builtin_amdgcn_mfma_f32_16x16x32_bf16(aA[rf], vA, acc[rf][cf], 0,0,0);
        #pragma unroll
        for (int rf=0;rf<2;rf++)
          acc[rf][cf] = __builtin_amdgcn_mfma_f32_16x16x32_bf16(aB[rf], vB, acc[rf][cf], 0,0,0);
      }
    }
  }

  // epilogue: out = leaky(acc); single-phase fp32 LDS transpose (32 rows)
  float* obuf = (float*)smem;   // 32 x 264 fp32 = 33792 B (xt dead)
  __syncthreads();
  #pragma unroll
  for (int cf=0;cf<4;cf++){
    int o = wave*64 + cf*16 + col;
    #pragma unroll
    for (int rf=0;rf<2;rf++)
      #pragma unroll
      for (int r=0;r<4;r++){
        int row = rf*16 + q*4 + r;
        float v = acc[rf][cf][r];
        v = v > 0.f ? v : 0.01f*v;
        obuf[row*264 + o] = v;
      }
  }
  __syncthreads();
  #pragma unroll
  for (int j=0;j<8;j++){
    int idx = j*256 + tid;
    int lrow = idx>>6, c4 = idx&63;
    int t = toks[lrow];
    if (t >= 0)
      *(f32x4*)&out[t*256 + c4*4] = *(const f32x4*)&obuf[lrow*264 + c4*4];
  }
}

// ---------------------------------------------------------------------------
extern "C" void kernel_launch(void* const* d_in, const int* in_sizes, int n_in,
                              void* d_out, int out_size, void* d_ws, size_t ws_size,
                              hipStream_t stream)
{
  const float* x   = (const float*)d_in[0];
  const float* Wr1 = (const float*)d_in[1];
  const float* br1 = (const float*)d_in[2];
  const float* Wr2 = (const float*)d_in[3];
  const float* br2 = (const float*)d_in[4];
  const float* We  = (const float*)d_in[5];
  const float* be  = (const float*)d_in[6];
  float* out = (float*)d_out;

  // Workspace layout (non-overlapping, 16B-aligned)
  char* ws = (char*)d_ws;
  ushort_t* WebP     = (ushort_t*)ws;                 // [0,        2097152)
  ushort_t* W1b      = (ushort_t*)(ws + 2097152);     // [2097152,  2228224)
  ushort_t* W2h      = (ushort_t*)(ws + 2228224);     // [2228224,  2236416)
  ushort_t* W2l      = (ushort_t*)(ws + 2236416);     // [2236416,  2244608)
  int*      pid      = (int*)(ws + 2244608);          // [2244608,  2506752)
  float2*   pAB      = (float2*)(ws + 2506752);       // [2506752,  3031040)
  int*      sortedTok= (int*)(ws + 3031040);          // [3031040,  3293184)
  int*      fixTok   = (int*)(ws + 3293184);          // [3293184,  3555328)
  int*      cnt      = (int*)(ws + 3555328);          // 256 ints
  int*      fixCnt   = cnt + 256;                     // 1 int
  int*      cur      = cnt + 272;                     // 256 ints
  int*      off      = cnt + 528;                     // 257 ints
  int*      tileOff  = cnt + 785;                     // 257 ints
  float*    Wr1T     = (float*)(ws + 3559504);        // 256KB fp32 transpose
  float*    Wr2T     = (float*)(ws + 3821648);        // 16KB fp32 transpose

  hipMemsetAsync(cnt, 0, 257*sizeof(int), stream);
  k_prep    <<<4096, 256, 0, stream>>>(We, Wr1, Wr2, WebP, W1b, W2h, W2l, Wr1T, Wr2T);
  r1r2_fused<<<1024, 256, 0, stream>>>(x, W1b, br1, W2h, W2l, br2, pid, pAB, fixCnt, fixTok);
  k_fixup   <<<512,  256, 0, stream>>>(x, Wr1T, br1, Wr2T, br2, fixCnt, fixTok, pid, pAB);
  k_hist    <<<256,  256, 0, stream>>>(pid, cnt);
  k_scan    <<<1,    256, 0, stream>>>(cnt, cur, off, tileOff);
  k_scatter <<<256,  256, 0, stream>>>(pid, cur, sortedTok);
  k_expert  <<<2304, 256, 0, stream>>>(x, WebP, be, off, tileOff, sortedTok, pAB, out);
}

// Round 5
// 307.447 us; speedup vs baseline: 1.2189x; 1.0181x over previous
//
#include <hip/hip_runtime.h>

typedef unsigned short ushort_t;
typedef __attribute__((ext_vector_type(8))) __bf16 bf16x8;
typedef __attribute__((ext_vector_type(4))) float f32x4;

#define MARGIN 1.5e-3f
#define FT 8    // fixup tokens per block
#define FTP 12  // padded row length for xsT (48B rows: 16B-aligned, vectorizable)

__device__ __forceinline__ float bf2f(ushort_t u){
  union { unsigned int i; float f; } v; v.i = ((unsigned int)u) << 16; return v.f;
}
__device__ __forceinline__ ushort_t f2bf(float f){
  union { float f; unsigned int i; } v; v.f = f;
  unsigned int x = v.i;
  return (ushort_t)((x + 0x7fffu + ((x >> 16) & 1u)) >> 16);
}
// async global->LDS, 16B per lane; LDS dest is wave-uniform base + lane*16
__device__ __forceinline__ void async_load16(const void* g, void* l){
  __builtin_amdgcn_global_load_lds((const __attribute__((address_space(1))) void*)g,
                                   (__attribute__((address_space(3))) void*)l, 16, 0, 0);
}

// ---------------------------------------------------------------------------
// prep: We -> bf16 FRAGMENT-PACKED  WP[e][n>>4][k>>3][n&15][k&7]  (k_expert
// reads B-fragments as one coalesced 1KB wave-load from L2). Wr1 -> bf16
// row-major (r1r2 stages it via global_load_lds). Wr2 -> bf16 hi+lo split.
// fp32 transposes Wr1T/Wr2T for the fp64 fixup kernel.
// ---------------------------------------------------------------------------
__global__ __launch_bounds__(256) void k_prep(const float* __restrict__ We,
    const float* __restrict__ Wr1, const float* __restrict__ Wr2,
    ushort_t* __restrict__ WebP, ushort_t* __restrict__ W1b,
    ushort_t* __restrict__ W2h, ushort_t* __restrict__ W2l,
    float* __restrict__ Wr1T, float* __restrict__ Wr2T)
{
  int idx = blockIdx.x*256 + threadIdx.x;
  if (idx < 1048576){
    int n = (idx >> 8) & 255, k = idx & 255;
    int dst = (idx & ~65535) + ((n>>4)<<12) + ((k>>3)<<7) + ((n&15)<<3) + (k&7);
    WebP[dst] = f2bf(We[idx]);
  }
  if (idx < 65536){
    W1b[idx] = f2bf(Wr1[idx]);
    int k = idx >> 8, o = idx & 255;          // coalesced write, strided read
    Wr1T[idx] = Wr1[o*256 + k];
  }
  if (idx < 4096){
    float w = Wr2[idx];
    ushort_t wh = f2bf(w);
    W2h[idx] = wh;
    W2l[idx] = f2bf(w - bf2f(wh));   // residual, captures next ~8 bits
    int k = idx >> 4, e = idx & 15;
    Wr2T[idx] = Wr2[e*256 + k];
  }
}

// ---------------------------------------------------------------------------
// Fused GEMM1 (bf16 MFMA) + logits MFMA + top2 + softmax + near-tie flagging.
// 64 tokens/block. Proven R7 version: x loads issued BEFORE the async B loads
// so the f2bf conversion's register wait doesn't drain the whole B stream.
// ---------------------------------------------------------------------------
__global__ __launch_bounds__(256) void r1r2_fused(const float* __restrict__ x,
    const ushort_t* __restrict__ W1b, const float* __restrict__ br1,
    const ushort_t* __restrict__ W2h, const ushort_t* __restrict__ W2l,
    const float* __restrict__ br2,
    int* __restrict__ pid, float2* __restrict__ pAB,
    int* __restrict__ fixCnt, int* __restrict__ fixTok)
{
  __shared__ __align__(16) char smem[46336];
  ushort_t* As = (ushort_t*)smem;              // 64 x 72
  char*     Bs = smem + 9216;                  // 256 rows x 128B, XOR-swizzled
  ushort_t* hB = (ushort_t*)smem;              // 64 x 264 (reuse after K-loop)
  float*    lg = (float*)(smem + 41984);       // 64 x 17
  const int tid = threadIdx.x;
  const int wave = tid>>6, lane = tid&63, q = lane>>4, col = lane&15;
  const int tok0 = blockIdx.x*64;

  f32x4 acc[4][4];
  #pragma unroll
  for (int i=0;i<4;i++)
    #pragma unroll
    for (int j=0;j<4;j++) acc[i][j] = f32x4{0.f,0.f,0.f,0.f};

  for (int kc = 0; kc < 4; ++kc){
    const int kb = kc*64;
    __syncthreads();
    // x loads FIRST (their latency overlaps the B async issue + latency)
    f32x4 xv[2][2];
    #pragma unroll
    for (int j=0;j<2;j++){
      int idx = j*256 + tid, row = idx>>3, c8 = idx&7;
      xv[j][0] = *(const f32x4*)&x[(tok0+row)*256 + kb + c8*8];
      xv[j][1] = *(const f32x4*)&x[(tok0+row)*256 + kb + c8*8 + 4];
    }
    // B: 32KB via global_load_lds; wave stages rows [wave*64, wave*64+64)
    #pragma unroll
    for (int i=0;i<8;i++){
      int r0 = wave*64 + i*8;
      int grow = r0 + (lane>>3);
      int kc8 = (lane&7) ^ (grow&7);
      async_load16(W1b + grow*256 + kb + kc8*8, Bs + r0*128);
    }
    // A: convert + write (waits only on x regs; B stream still in flight)
    #pragma unroll
    for (int j=0;j<2;j++){
      int idx = j*256 + tid, row = idx>>3, c8 = idx&7;
      union { uint4 u; ushort_t s[8]; } pk;
      pk.s[0]=f2bf(xv[j][0][0]); pk.s[1]=f2bf(xv[j][0][1]); pk.s[2]=f2bf(xv[j][0][2]); pk.s[3]=f2bf(xv[j][0][3]);
      pk.s[4]=f2bf(xv[j][1][0]); pk.s[5]=f2bf(xv[j][1][1]); pk.s[6]=f2bf(xv[j][1][2]); pk.s[7]=f2bf(xv[j][1][3]);
      *(uint4*)&As[row*72 + c8*8] = pk.u;
    }
    __syncthreads();
    #pragma unroll
    for (int kk=0;kk<2;kk++){
      bf16x8 a[4], b[4];
      #pragma unroll
      for (int rf=0;rf<4;rf++) a[rf] = *(const bf16x8*)&As[(rf*16+col)*72 + kk*32 + q*8];
      #pragma unroll
      for (int cf=0;cf<4;cf++){
        int n = wave*64 + cf*16 + col;
        b[cf] = *(const bf16x8*)(Bs + n*128 + (((kk*4+q) ^ (n&7))*16));
      }
      #pragma unroll
      for (int rf=0;rf<4;rf++)
        #pragma unroll
        for (int cf=0;cf<4;cf++)
          acc[rf][cf] = __builtin_amdgcn_mfma_f32_16x16x32_bf16(a[rf], b[cf], acc[rf][cf], 0,0,0);
    }
  }
  __syncthreads();
  // h = leaky(acc + br1) -> bf16 into hB
  {
    float br1v[4];
    #pragma unroll
    for (int cf=0;cf<4;cf++) br1v[cf] = br1[wave*64 + cf*16 + col];
    #pragma unroll
    for (int rf=0;rf<4;rf++)
      #pragma unroll
      for (int cf=0;cf<4;cf++){
        int o = wave*64 + cf*16 + col;
        #pragma unroll
        for (int r=0;r<4;r++){
          int row = rf*16 + q*4 + r;
          float p = acc[rf][cf][r] + br1v[cf];
          p = p > 0.f ? p : 0.01f*p;
          hB[row*264 + o] = f2bf(p);
        }
      }
  }
  __syncthreads();
  // logits[64x16] = h @ Wr2^T via MFMA; wave handles its 16-token m-tile
  {
    f32x4 acc2 = f32x4{0.f,0.f,0.f,0.f};
    #pragma unroll
    for (int c2=0;c2<8;c2++){
      bf16x8 a2 = *(const bf16x8*)&hB[(wave*16+col)*264 + c2*32 + q*8];
      bf16x8 bh = *(const bf16x8*)&W2h[col*256 + c2*32 + q*8];
      bf16x8 bl = *(const bf16x8*)&W2l[col*256 + c2*32 + q*8];
      acc2 = __builtin_amdgcn_mfma_f32_16x16x32_bf16(a2, bh, acc2, 0,0,0);
      acc2 = __builtin_amdgcn_mfma_f32_16x16x32_bf16(a2, bl, acc2, 0,0,0);
    }
    #pragma unroll
    for (int r=0;r<4;r++) lg[(wave*16 + q*4 + r)*17 + col] = acc2[r];
  }
  __syncthreads();
  if (tid < 64){
    const int tok = tok0 + tid;
    float v[16];
    #pragma unroll
    for (int e=0;e<16;e++) v[e] = lg[tid*17 + e] + br2[e];
    float best=-3.4e38f, sec=-3.4e38f, thr=-3.4e38f; int b1=0, b2=0;
    #pragma unroll
    for (int e=0;e<16;e++){
      float val = v[e];
      if (val > best){ thr=sec; sec=best; b2=b1; best=val; b1=e; }
      else if (val > sec){ thr=sec; sec=val; b2=e; }
      else if (val > thr){ thr=val; }
    }
    float ex = expf(sec - best);
    float s = 1.f + ex;
    float p1 = 1.f/s, p2 = ex/s;
    int eA = b1 < b2 ? b1 : b2;
    int eB = b1 < b2 ? b2 : b1;
    float pA = b1 < b2 ? p1 : p2;
    float pB = b1 < b2 ? p2 : p1;
    pid[tok] = eA*16 + eB;
    pAB[tok] = make_float2(pA, pB);
    if (sec - thr < MARGIN){
      int slot = atomicAdd(fixCnt, 1);
      fixTok[slot] = tok;
    }
  }
}

// ---------------------------------------------------------------------------
// fp64 exact router recompute for near-tie tokens (coalesced transposed
// weights; xsT broadcast reads).
// ---------------------------------------------------------------------------
__global__ __launch_bounds__(256) void k_fixup(const float* __restrict__ x,
    const float* __restrict__ Wr1T, const float* __restrict__ br1,
    const float* __restrict__ Wr2T, const float* __restrict__ br2,
    const int* __restrict__ fixCnt, const int* __restrict__ fixTok,
    int* __restrict__ pid, float2* __restrict__ pAB)
{
  __shared__ __align__(16) float xsT[256][FTP];  // 12 KB, rows 48B (16B-aligned)
  __shared__ double hs[FT*256];                  // 16 KB
  __shared__ double lgs[FT][16];
  const int tid = threadIdx.x;
  const int n = *fixCnt;
  for (int base = blockIdx.x*FT; base < n; base += gridDim.x*FT){
    const int nt = min(FT, n - base);
    __syncthreads();
    // stage x for up to FT tokens, transposed: xsT[c][t]
    for (int i = tid; i < nt*256; i += 256){
      int t = i >> 8, c = i & 255;               // coalesced read per token row
      xsT[c][t] = x[fixTok[base + t]*256 + c];
    }
    __syncthreads();
    // layer 1: thread o computes h[t][o] for all FT tokens.
    {
      const int o = tid;
      double acc[FT];
      #pragma unroll
      for (int t=0;t<FT;t++) acc[t] = 0.0;
      #pragma unroll 4
      for (int k=0;k<256;k++){
        double w = (double)Wr1T[k*256 + o];
        #pragma unroll
        for (int t=0;t<FT;t++)
          acc[t] += (double)xsT[k][t] * w;
      }
      double b = (double)br1[o];
      #pragma unroll
      for (int t=0;t<FT;t++){
        double v = acc[t] + b;
        hs[t*256 + o] = v > 0.0 ? v : 0.01*v;
      }
    }
    __syncthreads();
    // layer 2: 128 threads, (t,e) = (tid>>4, tid&15); Wr2T[k*16+e] coalesced
    if (tid < FT*16){
      const int t = tid >> 4, e = tid & 15;
      double a0=0, a1=0;
      #pragma unroll 4
      for (int k=0;k<256;k+=2){
        a0 += hs[t*256 + k]     * (double)Wr2T[k*16 + e];
        a1 += hs[t*256 + k + 1] * (double)Wr2T[(k+1)*16 + e];
      }
      lgs[t][e] = (a0 + a1) + (double)br2[e];
    }
    __syncthreads();
    if (tid < nt){
      const int tok = fixTok[base + tid];
      double best=-1e300, sec=-1e300; int b1=0, b2=0;
      #pragma unroll
      for (int e=0;e<16;e++){
        double val = lgs[tid][e];
        if (val > best){ sec=best; b2=b1; best=val; b1=e; }
        else if (val > sec){ sec=val; b2=e; }
      }
      double ex = exp(sec - best);
      double s = 1.0 + ex;
      double p1 = 1.0/s, p2 = ex/s;
      int eA = b1 < b2 ? b1 : b2;
      int eB = b1 < b2 ? b2 : b1;
      float pA = (float)(b1 < b2 ? p1 : p2);
      float pB = (float)(b1 < b2 ? p2 : p1);
      pid[tok] = eA*16 + eB;
      pAB[tok] = make_float2(pA, pB);
    }
  }
}

__global__ __launch_bounds__(256) void k_hist(const int* __restrict__ pid, int* __restrict__ cnt)
{
  __shared__ int hc[256];
  const int tid = threadIdx.x;
  hc[tid] = 0; __syncthreads();
  atomicAdd(&hc[pid[blockIdx.x*256 + tid]], 1);
  __syncthreads();
  if (hc[tid]) atomicAdd(&cnt[tid], hc[tid]);
}

// tiles are 32 tokens: tc = ceil(c/32)
__global__ __launch_bounds__(256) void k_scan(int* __restrict__ cnt, int* __restrict__ cur,
    int* __restrict__ off, int* __restrict__ tileOff)
{
  __shared__ int sc[256];
  const int tid = threadIdx.x;
  int c = cnt[tid];
  sc[tid] = c; __syncthreads();
  for (int s=1;s<256;s<<=1){ int v = (tid>=s)? sc[tid-s]:0; __syncthreads(); sc[tid]+=v; __syncthreads(); }
  int inc = sc[tid];
  off[tid] = inc - c;
  cur[tid] = inc - c;
  if (tid==255) off[256] = inc;
  int tc = (c+31)>>5;
  __syncthreads();
  sc[tid] = tc; __syncthreads();
  for (int s=1;s<256;s<<=1){ int v = (tid>=s)? sc[tid-s]:0; __syncthreads(); sc[tid]+=v; __syncthreads(); }
  tileOff[tid] = sc[tid] - tc;
  if (tid==255) tileOff[256] = sc[tid];
}

__global__ __launch_bounds__(256) void k_scatter(const int* __restrict__ pid,
    int* __restrict__ cur, int* __restrict__ sortedTok)
{
  int b = blockIdx.x*256 + threadIdx.x;
  int p = pid[b];
  int slot = atomicAdd(&cur[p], 1);
  sortedTok[slot] = b;
}

// ---------------------------------------------------------------------------
// Expert pair GEMM — R10:
//  * R9 structure (32-token tiles, dual prob-scaled A, single acc, packed-B
//    from L2, no K-loop barriers) PLUS explicit register double-buffer for
//    the 8 B-fragments: step s issues s+1's loads before s's MFMAs, so
//    vmcnt(8) leaves the next step's loads in flight (R9 post-mortem: at
//    VGPR=64 the compiler serialized load->wait->MFMA, exposing full L2
//    latency 64x per wave).
// ---------------------------------------------------------------------------
__global__ __launch_bounds__(256) void k_expert(const float* __restrict__ x,
    const ushort_t* __restrict__ WebP, const float* __restrict__ be,
    const int* __restrict__ off, const int* __restrict__ tileOff,
    const int* __restrict__ sortedTok, const float2* __restrict__ pAB,
    float* __restrict__ out)
{
  const int totTiles = tileOff[256];
  const int bid = blockIdx.x;
  if (bid >= totTiles) return;
  __shared__ __align__(16) char smem[34048];
  ushort_t* xtA = (ushort_t*)smem;            // 32 rows x 512B  [0, 16384)
  ushort_t* xtB = (ushort_t*)(smem + 16384);  // 32 rows x 512B  [16384, 32768)
  __shared__ int toks[32];
  __shared__ float pAs[32], pBs[32];
  __shared__ int sh_p;
  const int tid = threadIdx.x;
  if (tid == 0){
    int lo=0, hi=255;
    while (lo < hi){ int mid=(lo+hi+1)>>1; if (tileOff[mid] <= bid) lo=mid; else hi=mid-1; }
    sh_p = lo;
  }
  __syncthreads();
  const int p = sh_p;
  const int tstart = off[p] + (bid - tileOff[p])*32;
  const int nt = min(32, off[p+1] - tstart);
  if (tid < 32){
    if (tid < nt){
      int t = sortedTok[tstart + tid];
      toks[tid] = t;
      float2 ab = pAB[t];
      pAs[tid] = ab.x; pBs[tid] = ab.y;
    } else { toks[tid] = -1; pAs[tid]=0.f; pBs[tid]=0.f; }
  }
  __syncthreads();

  // stage dual prob-scaled x-tiles (pad rows: probs=0 -> zeros, never stored)
  #pragma unroll
  for (int j=0;j<4;j++){
    int ci = j*256 + tid, row = ci>>5, c = ci&31;
    int t = toks[row]; t = t < 0 ? 0 : t;
    float pA = pAs[row], pB = pBs[row];
    f32x4 v0 = *(const f32x4*)&x[t*256 + c*8];
    f32x4 v1 = *(const f32x4*)&x[t*256 + c*8 + 4];
    union { uint4 u; ushort_t s[8]; } pk;
    pk.s[0]=f2bf(v0[0]*pA); pk.s[1]=f2bf(v0[1]*pA); pk.s[2]=f2bf(v0[2]*pA); pk.s[3]=f2bf(v0[3]*pA);
    pk.s[4]=f2bf(v1[0]*pA); pk.s[5]=f2bf(v1[1]*pA); pk.s[6]=f2bf(v1[2]*pA); pk.s[7]=f2bf(v1[3]*pA);
    *(uint4*)&xtA[row*256 + ((c ^ (row&7))<<3)] = pk.u;
    pk.s[0]=f2bf(v0[0]*pB); pk.s[1]=f2bf(v0[1]*pB); pk.s[2]=f2bf(v0[2]*pB); pk.s[3]=f2bf(v0[3]*pB);
    pk.s[4]=f2bf(v1[0]*pB); pk.s[5]=f2bf(v1[1]*pB); pk.s[6]=f2bf(v1[2]*pB); pk.s[7]=f2bf(v1[3]*pB);
    *(uint4*)&xtB[row*256 + ((c ^ (row&7))<<3)] = pk.u;
  }
  __syncthreads();

  const int wave = tid>>6, lane = tid&63, q = lane>>4, col = lane&15;
  const int eA = p >> 4, eB = p & 15;

  // acc init = pA*bA + pB*bB per element (row-dependent probs, col-dep bias)
  float pa_r[8], pb_r[8];
  #pragma unroll
  for (int rf=0;rf<2;rf++)
    #pragma unroll
    for (int r=0;r<4;r++){
      int row = rf*16 + q*4 + r;
      pa_r[rf*4+r] = pAs[row]; pb_r[rf*4+r] = pBs[row];
    }
  f32x4 acc[2][4];
  #pragma unroll
  for (int cf=0;cf<4;cf++){
    int o = wave*64 + cf*16 + col;
    float bA_ = be[eA*256 + o], bB_ = be[eB*256 + o];
    #pragma unroll
    for (int rf=0;rf<2;rf++)
      #pragma unroll
      for (int r=0;r<4;r++)
        acc[rf][cf][r] = pa_r[rf*4+r]*bA_ + pb_r[rf*4+r]*bB_;
  }

  // K-loop: no barriers; explicit double-buffered B fragments. Step s
  // (s = kc*2+kk, 8 steps): B frag offset = cf*4096 + s*512 ushorts;
  // A k-index k8 = 4*s + q.
  const ushort_t* bAp = WebP + eA*65536 + (wave*4)*4096 + q*128 + col*8;
  const ushort_t* bBp = WebP + eB*65536 + (wave*4)*4096 + q*128 + col*8;

  bf16x8 bufA[2][4], bufB[2][4];
  #pragma unroll
  for (int cf=0;cf<4;cf++){
    bufA[0][cf] = *(const bf16x8*)&bAp[cf*4096];
    bufB[0][cf] = *(const bf16x8*)&bBp[cf*4096];
  }
  #pragma unroll
  for (int s=0;s<8;s++){
    const int cb = s & 1, nb = cb ^ 1;
    // (1) issue next step's 8 B loads into the alternate buffer (newer in
    //     vmcnt order -> MFMAs below wait only on the current buffer)
    if (s < 7){
      #pragma unroll
      for (int cf=0;cf<4;cf++){
        bufA[nb][cf] = *(const bf16x8*)&bAp[cf*4096 + (s+1)*512];
        bufB[nb][cf] = *(const bf16x8*)&bBp[cf*4096 + (s+1)*512];
      }
    }
    // (2) A fragments from LDS (independent counter; overlaps B wait)
    const int k8 = 4*s + q;
    bf16x8 aA[2], aB[2];
    #pragma unroll
    for (int rf=0;rf<2;rf++){
      aA[rf] = *(const bf16x8*)&xtA[(rf*16+col)*256 + ((k8 ^ (col&7))<<3)];
      aB[rf] = *(const bf16x8*)&xtB[(rf*16+col)*256 + ((k8 ^ (col&7))<<3)];
    }
    // (3) 16 MFMAs on the current buffer
    #pragma unroll
    for (int cf=0;cf<4;cf++){
      #pragma unroll
      for (int rf=0;rf<2;rf++)
        acc[rf][cf] = __builtin_amdgcn_mfma_f32_16x16x32_bf16(aA[rf], bufA[cb][cf], acc[rf][cf], 0,0,0);
      #pragma unroll
      for (int rf=0;rf<2;rf++)
        acc[rf][cf] = __builtin_amdgcn_mfma_f32_16x16x32_bf16(aB[rf], bufB[cb][cf], acc[rf][cf], 0,0,0);
    }
  }

  // epilogue: out = leaky(acc); single-phase fp32 LDS transpose (32 rows)
  float* obuf = (float*)smem;   // 32 x 264 fp32 = 33792 B (xt dead)
  __syncthreads();
  #pragma unroll
  for (int cf=0;cf<4;cf++){
    int o = wave*64 + cf*16 + col;
    #pragma unroll
    for (int rf=0;rf<2;rf++)
      #pragma unroll
      for (int r=0;r<4;r++){
        int row = rf*16 + q*4 + r;
        float v = acc[rf][cf][r];
        v = v > 0.f ? v : 0.01f*v;
        obuf[row*264 + o] = v;
      }
  }
  __syncthreads();
  #pragma unroll
  for (int j=0;j<8;j++){
    int idx = j*256 + tid;
    int lrow = idx>>6, c4 = idx&63;
    int t = toks[lrow];
    if (t >= 0)
      *(f32x4*)&out[t*256 + c4*4] = *(const f32x4*)&obuf[lrow*264 + c4*4];
  }
}

// ---------------------------------------------------------------------------
extern "C" void kernel_launch(void* const* d_in, const int* in_sizes, int n_in,
                              void* d_out, int out_size, void* d_ws, size_t ws_size,
                              hipStream_t stream)
{
  const float* x   = (const float*)d_in[0];
  const float* Wr1 = (const float*)d_in[1];
  const float* br1 = (const float*)d_in[2];
  const float* Wr2 = (const float*)d_in[3];
  const float* br2 = (const float*)d_in[4];
  const float* We  = (const float*)d_in[5];
  const float* be  = (const float*)d_in[6];
  float* out = (float*)d_out;

  // Workspace layout (non-overlapping, 16B-aligned)
  char* ws = (char*)d_ws;
  ushort_t* WebP     = (ushort_t*)ws;                 // [0,        2097152)
  ushort_t* W1b      = (ushort_t*)(ws + 2097152);     // [2097152,  2228224)
  ushort_t* W2h      = (ushort_t*)(ws + 2228224);     // [2228224,  2236416)
  ushort_t* W2l      = (ushort_t*)(ws + 2236416);     // [2236416,  2244608)
  int*      pid      = (int*)(ws + 2244608);          // [2244608,  2506752)
  float2*   pAB      = (float2*)(ws + 2506752);       // [2506752,  3031040)
  int*      sortedTok= (int*)(ws + 3031040);          // [3031040,  3293184)
  int*      fixTok   = (int*)(ws + 3293184);          // [3293184,  3555328)
  int*      cnt      = (int*)(ws + 3555328);          // 256 ints
  int*      fixCnt   = cnt + 256;                     // 1 int
  int*      cur      = cnt + 272;                     // 256 ints
  int*      off      = cnt + 528;                     // 257 ints
  int*      tileOff  = cnt + 785;                     // 257 ints
  float*    Wr1T     = (float*)(ws + 3559504);        // 256KB fp32 transpose
  float*    Wr2T     = (float*)(ws + 3821648);        // 16KB fp32 transpose

  hipMemsetAsync(cnt, 0, 257*sizeof(int), stream);
  k_prep    <<<4096, 256, 0, stream>>>(We, Wr1, Wr2, WebP, W1b, W2h, W2l, Wr1T, Wr2T);
  r1r2_fused<<<1024, 256, 0, stream>>>(x, W1b, br1, W2h, W2l, br2, pid, pAB, fixCnt, fixTok);
  k_fixup   <<<512,  256, 0, stream>>>(x, Wr1T, br1, Wr2T, br2, fixCnt, fixTok, pid, pAB);
  k_hist    <<<256,  256, 0, stream>>>(pid, cnt);
  k_scan    <<<1,    256, 0, stream>>>(cnt, cur, off, tileOff);
  k_scatter <<<256,  256, 0, stream>>>(pid, cur, sortedTok);
  k_expert  <<<2304, 256, 0, stream>>>(x, WebP, be, off, tileOff, sortedTok, pAB, out);
}